// Round 9
// baseline (145.243 us; speedup 1.0000x reference)
//
#include <hip/hip_runtime.h>
#include <math.h>

#define TS 1024               // dg/G table size
#define NPTS 16384            // N per row
#define NROWS 256             // B
#define GPAD 5                // G entry i stored at (i>>2)*5 + (i&3); gcd(5,32)=1

// softplus via hardware transcendentals (v_exp_f32 / v_log_f32)
__device__ __forceinline__ float softplus(float x) {
    float ax = fabsf(x);
    return fmaxf(x, 0.0f) + __logf(1.0f + __expf(-ax));
}

// G-table lookup from grouped-pad LDS: entry i at (i>>2)*GPAD + (i&3)
__device__ __forceinline__ float G_lookup(const float* __restrict__ Gl, float t) {
    const float scale = (float)(TS - 1) / 10.0f;
    float x = t * scale;
    x = fminf(fmaxf(x, 0.0f), (float)(TS - 1));
    int i = (int)x;
    if (i > TS - 2) i = TS - 2;
    float f = x - (float)i;
    int i1 = i + 1;
    float a = Gl[(i  >> 2) * GPAD + (i  & 3)];
    float b = Gl[(i1 >> 2) * GPAD + (i1 & 3)];
    return fmaf(b - a, f, a);
}

// Single fused kernel, 1024 blocks x 256 threads.
// Phase 1: block i computes dg(t_i) cooperatively (k-split across threads,
//   shfl_xor partial reduction, VMEM per-lane weight reads -> L2-hot),
//   publishes entry + release-add on a counter (poison-offset target).
// Sync: tid0 acquire-spins until all 1024 published (short window, no
//   concurrent streaming -- avoids R6's lookback L2-invalidate storm).
//   __launch_bounds__(256,4) => >=4 blocks/CU co-resident = 1024 ✓;
//   producers publish BEFORE waiting => deadlock-free.
// Phase 2: R8-proven G prelude (LDS antiderivative) + quarter-row map.
__global__ __launch_bounds__(256, 4) void fused(
    const float* __restrict__ t,
    const float* __restrict__ W1, const float* __restrict__ b1,
    const float* __restrict__ W2, const float* __restrict__ b2,
    const float* __restrict__ W3, const float* __restrict__ b3,
    const float* __restrict__ W4, const float* __restrict__ b4,
    const float* __restrict__ W5, const float* __restrict__ b5,
    float* __restrict__ dgtab,
    unsigned int* __restrict__ count,
    float* __restrict__ out)
{
    __shared__ float hA[64], hB[64];
    __shared__ float Gl[(TS / 4) * GPAD];   // 1280 floats = 5 KB
    __shared__ float woffs[4];

    const int tid  = threadIdx.x;
    const int lane = tid & 63;
    const int wave = tid >> 6;
    const int blk  = blockIdx.x;

    // ======== Phase 1: compute dg at grid point i = blk ========
    const float te = 10.0f * (float)blk / (float)(TS - 1);

    // L1: 1 -> 32 (threads 0..31)
    if (tid < 32) hA[tid] = softplus(fmaf(te, W1[tid], b1[tid]));
    __syncthreads();

    // L2: 32 -> 64. thread: j = tid>>2, k-quarter q = tid&3 (8 k's)
    {
        const int j = tid >> 2, q = tid & 3;
        const float4* wp = (const float4*)(W2 + j * 32 + q * 8);
        float4 wa = wp[0], wb = wp[1];
        const float* hk = hA + q * 8;
        float a = 0.0f;
        a = fmaf(wa.x, hk[0], a); a = fmaf(wa.y, hk[1], a);
        a = fmaf(wa.z, hk[2], a); a = fmaf(wa.w, hk[3], a);
        a = fmaf(wb.x, hk[4], a); a = fmaf(wb.y, hk[5], a);
        a = fmaf(wb.z, hk[6], a); a = fmaf(wb.w, hk[7], a);
        a += __shfl_xor(a, 1, 64);
        a += __shfl_xor(a, 2, 64);
        float bj = b2[j];
        if (q == 0) hB[j] = softplus(a + bj);
    }
    __syncthreads();

    // L3: 64 -> 64. thread: j = tid>>2, k-quarter q = tid&3 (16 k's)
    {
        const int j = tid >> 2, q = tid & 3;
        const float4* wp = (const float4*)(W3 + j * 64 + q * 16);
        const float* hk = hB + q * 16;
        float a = 0.0f;
#pragma unroll
        for (int m = 0; m < 4; ++m) {
            float4 wv = wp[m];
            a = fmaf(wv.x, hk[m * 4 + 0], a);
            a = fmaf(wv.y, hk[m * 4 + 1], a);
            a = fmaf(wv.z, hk[m * 4 + 2], a);
            a = fmaf(wv.w, hk[m * 4 + 3], a);
        }
        a += __shfl_xor(a, 1, 64);
        a += __shfl_xor(a, 2, 64);
        float bj = b3[j];
        if (q == 0) hA[j] = softplus(a + bj);
    }
    __syncthreads();

    // L4: 64 -> 32. thread: j = tid>>3, k-eighth o = tid&7 (8 k's)
    {
        const int j = tid >> 3, o = tid & 7;
        const float4* wp = (const float4*)(W4 + j * 64 + o * 8);
        float4 wa = wp[0], wb = wp[1];
        const float* hk = hA + o * 8;
        float a = 0.0f;
        a = fmaf(wa.x, hk[0], a); a = fmaf(wa.y, hk[1], a);
        a = fmaf(wa.z, hk[2], a); a = fmaf(wa.w, hk[3], a);
        a = fmaf(wb.x, hk[4], a); a = fmaf(wb.y, hk[5], a);
        a = fmaf(wb.z, hk[6], a); a = fmaf(wb.w, hk[7], a);
        a += __shfl_xor(a, 1, 64);
        a += __shfl_xor(a, 2, 64);
        a += __shfl_xor(a, 4, 64);
        float bj = b4[j];
        if (o == 0) hB[j] = softplus(a + bj);
    }
    __syncthreads();

    // L5: 32 -> 1, +1.0 (wave 0); publish entry + counter
    if (tid < 64) {
        float a = (lane < 32) ? hB[lane] * W5[lane] : 0.0f;
        a += __shfl_xor(a, 1, 64);
        a += __shfl_xor(a, 2, 64);
        a += __shfl_xor(a, 4, 64);
        a += __shfl_xor(a, 8, 64);
        a += __shfl_xor(a, 16, 64);
        if (lane == 0) {
            float dgv = softplus(a + b5[0]) + 1.0f;
            dgtab[blk] = dgv;
            // release: drains the store, flushes to coherence point
            __hip_atomic_fetch_add(count, 1u, __ATOMIC_RELEASE,
                                   __HIP_MEMORY_SCOPE_AGENT);
        }
    }

    // ======== Sync: wait for all 1024 entries ========
    if (tid == 0) {
        const unsigned int target = 0xAAAAAAAAu + gridDim.x;  // ws poison base
        while (__hip_atomic_load(count, __ATOMIC_ACQUIRE,
                                 __HIP_MEMORY_SCOPE_AGENT) != target)
            __builtin_amdgcn_s_sleep(2);
    }
    __syncthreads();

    // ======== Phase 2: build G in LDS, then map quarter row ========
    // dg reads as relaxed agent-scope atomics: coherent across XCDs.
    float4 dv;
    {
        const float* dp = dgtab + tid * 4;
        dv.x = __hip_atomic_load(dp + 0, __ATOMIC_RELAXED, __HIP_MEMORY_SCOPE_AGENT);
        dv.y = __hip_atomic_load(dp + 1, __ATOMIC_RELAXED, __HIP_MEMORY_SCOPE_AGENT);
        dv.z = __hip_atomic_load(dp + 2, __ATOMIC_RELAXED, __HIP_MEMORY_SCOPE_AGENT);
        dv.w = __hip_atomic_load(dp + 3, __ATOMIC_RELAXED, __HIP_MEMORY_SCOPE_AGENT);
    }
    const float dg0 = __hip_atomic_load(dgtab, __ATOMIC_RELAXED,
                                        __HIP_MEMORY_SCOPE_AGENT);

    // serial inclusive prefix of 4
    float p0 = dv.x;
    float p1 = p0 + dv.y;
    float p2 = p1 + dv.z;
    float p3 = p2 + dv.w;
    float s  = p3;

    // wave scan of per-thread totals
    float v = s;
#pragma unroll
    for (int d = 1; d < 64; d <<= 1) {
        float u = __shfl_up(v, d, 64);
        if (lane >= d) v += u;
    }
    if (lane == 63) woffs[wave] = v;
    __syncthreads();
    float excl = v - s;
#pragma unroll
    for (int w = 0; w < 3; ++w)
        excl += (w < wave) ? woffs[w] : 0.0f;

    // write G slice: G[i] = h*(P[i] - (dg0+dg[i])/2)
    const float h = 10.0f / (float)(TS - 1);
    float* myG = &Gl[tid * GPAD];
    myG[0] = h * (excl + p0 - 0.5f * (dg0 + dv.x));
    myG[1] = h * (excl + p1 - 0.5f * (dg0 + dv.y));
    myG[2] = h * (excl + p2 - 0.5f * (dg0 + dv.z));
    myG[3] = h * (excl + p3 - 0.5f * (dg0 + dv.w));
    __syncthreads();

    // map 4096 t's (quarter row)
    const int row     = blk >> 2;        // 0..255
    const int quarter = blk & 3;         // 0..3
    const float* tr = t + (size_t)row * NPTS;
    float*       gr = out + (size_t)row * NPTS;
    const int base  = quarter * 4096 + tid * 16;

    const float G0 = G_lookup(Gl, tr[0]);   // tr[0] block-uniform

    const float4* p = (const float4*)(tr + base);
    float4*      g4 = (float4*)(gr + base);
#pragma unroll
    for (int q = 0; q < 4; ++q) {
        float4 a4 = p[q];
        float4 o;
        o.x = G_lookup(Gl, a4.x) - G0;
        o.y = G_lookup(Gl, a4.y) - G0;
        o.z = G_lookup(Gl, a4.z) - G0;
        o.w = G_lookup(Gl, a4.w) - G0;
        g4[q] = o;
    }
}

extern "C" void kernel_launch(void* const* d_in, const int* in_sizes, int n_in,
                              void* d_out, int out_size, void* d_ws, size_t ws_size,
                              hipStream_t stream)
{
    const float* t  = (const float*)d_in[0];
    const float* W1 = (const float*)d_in[1];
    const float* b1 = (const float*)d_in[2];
    const float* W2 = (const float*)d_in[3];
    const float* b2 = (const float*)d_in[4];
    const float* W3 = (const float*)d_in[5];
    const float* b3 = (const float*)d_in[6];
    const float* W4 = (const float*)d_in[7];
    const float* b4 = (const float*)d_in[8];
    const float* W5 = (const float*)d_in[9];
    const float* b5 = (const float*)d_in[10];
    float* dgtab = (float*)d_ws;                                   // 4 KB
    unsigned int* count = (unsigned int*)((char*)d_ws + (1 << 20)); // +1 MB
    float* out   = (float*)d_out;

    fused<<<NROWS * 4, 256, 0, stream>>>(t, W1, b1, W2, b2, W3, b3, W4, b4,
                                         W5, b5, dgtab, count, out);
}

// Round 10
// 117.943 us; speedup vs baseline: 1.2315x; 1.2315x over previous
//
#include <hip/hip_runtime.h>
#include <math.h>

#define TS 1024               // dg/G table size == gridDim
#define NPTS 16384            // N per row
#define NROWS 256             // B
#define GPAD 5                // G entry i stored at (i>>2)*5 + (i&3); gcd(5,32)=1

// softplus via hardware transcendentals (v_exp_f32 / v_log_f32)
__device__ __forceinline__ float softplus(float x) {
    float ax = fabsf(x);
    return fmaxf(x, 0.0f) + __logf(1.0f + __expf(-ax));
}

// G-table lookup from grouped-pad LDS: entry i at (i>>2)*GPAD + (i&3)
__device__ __forceinline__ float G_lookup(const float* __restrict__ Gl, float t) {
    const float scale = (float)(TS - 1) / 10.0f;
    float x = t * scale;
    x = fminf(fmaxf(x, 0.0f), (float)(TS - 1));
    int i = (int)x;
    if (i > TS - 2) i = TS - 2;
    float f = x - (float)i;
    int i1 = i + 1;
    float a = Gl[(i  >> 2) * GPAD + (i  & 3)];
    float b = Gl[(i1 >> 2) * GPAD + (i1 & 3)];
    return fmaf(b - a, f, a);
}

// Self-signaling spin: dg values are >= 1.0; d_ws poison 0xAAAAAAAA reads
// as -3e-13. Relaxed agent-scope load sees either poison or the final
// value (4B atomic store, no tearing). No counter, no RMW -- R9's 80us
// was 1024 serialized RMWs + spinners on ONE cacheline.
__device__ __forceinline__ float spin_load(const float* p) {
    float v = __hip_atomic_load(p, __ATOMIC_RELAXED, __HIP_MEMORY_SCOPE_AGENT);
    while (!(v > 0.5f)) {
        __builtin_amdgcn_s_sleep(4);
        v = __hip_atomic_load(p, __ATOMIC_RELAXED, __HIP_MEMORY_SCOPE_AGENT);
    }
    return v;
}

// Single fused kernel, 1024 blocks x 256 threads.
// Phase 1: block i computes dg(t_i) cooperatively (R9-proven k-split MLP),
//   release-stores its entry (distinct address per block).
// Sync: each thread prefetches its t data, then spins on its OWN 4 dg
//   entries (self-signaling values, s_sleep backoff). All 1024 blocks are
//   co-resident (VGPR~32, LDS 6KB -> >=8 blocks/CU; 2048 slots > 1024),
//   and producers publish before consuming => deadlock-free.
// Phase 2: R8-proven G prelude (LDS antiderivative) + quarter-row map.
__global__ __launch_bounds__(256, 4) void fused(
    const float* __restrict__ t,
    const float* __restrict__ W1, const float* __restrict__ b1,
    const float* __restrict__ W2, const float* __restrict__ b2,
    const float* __restrict__ W3, const float* __restrict__ b3,
    const float* __restrict__ W4, const float* __restrict__ b4,
    const float* __restrict__ W5, const float* __restrict__ b5,
    float* __restrict__ dgtab,
    float* __restrict__ out)
{
    __shared__ float hA[64], hB[64];
    __shared__ float Gl[(TS / 4) * GPAD];   // 1280 floats = 5 KB
    __shared__ float woffs[4];
    __shared__ float shdg0;

    const int tid  = threadIdx.x;
    const int lane = tid & 63;
    const int wave = tid >> 6;
    const int blk  = blockIdx.x;

    // ======== Phase 1: compute dg at grid point i = blk ========
    const float te = 10.0f * (float)blk / (float)(TS - 1);

    // L1: 1 -> 32 (threads 0..31)
    if (tid < 32) hA[tid] = softplus(fmaf(te, W1[tid], b1[tid]));
    __syncthreads();

    // L2: 32 -> 64. thread: j = tid>>2, k-quarter q = tid&3 (8 k's)
    {
        const int j = tid >> 2, q = tid & 3;
        const float4* wp = (const float4*)(W2 + j * 32 + q * 8);
        float4 wa = wp[0], wb = wp[1];
        const float* hk = hA + q * 8;
        float a = 0.0f;
        a = fmaf(wa.x, hk[0], a); a = fmaf(wa.y, hk[1], a);
        a = fmaf(wa.z, hk[2], a); a = fmaf(wa.w, hk[3], a);
        a = fmaf(wb.x, hk[4], a); a = fmaf(wb.y, hk[5], a);
        a = fmaf(wb.z, hk[6], a); a = fmaf(wb.w, hk[7], a);
        a += __shfl_xor(a, 1, 64);
        a += __shfl_xor(a, 2, 64);
        float bj = b2[j];
        if (q == 0) hB[j] = softplus(a + bj);
    }
    __syncthreads();

    // L3: 64 -> 64. thread: j = tid>>2, k-quarter q = tid&3 (16 k's)
    {
        const int j = tid >> 2, q = tid & 3;
        const float4* wp = (const float4*)(W3 + j * 64 + q * 16);
        const float* hk = hB + q * 16;
        float a = 0.0f;
#pragma unroll
        for (int m = 0; m < 4; ++m) {
            float4 wv = wp[m];
            a = fmaf(wv.x, hk[m * 4 + 0], a);
            a = fmaf(wv.y, hk[m * 4 + 1], a);
            a = fmaf(wv.z, hk[m * 4 + 2], a);
            a = fmaf(wv.w, hk[m * 4 + 3], a);
        }
        a += __shfl_xor(a, 1, 64);
        a += __shfl_xor(a, 2, 64);
        float bj = b3[j];
        if (q == 0) hA[j] = softplus(a + bj);
    }
    __syncthreads();

    // L4: 64 -> 32. thread: j = tid>>3, k-eighth o = tid&7 (8 k's)
    {
        const int j = tid >> 3, o = tid & 7;
        const float4* wp = (const float4*)(W4 + j * 64 + o * 8);
        float4 wa = wp[0], wb = wp[1];
        const float* hk = hA + o * 8;
        float a = 0.0f;
        a = fmaf(wa.x, hk[0], a); a = fmaf(wa.y, hk[1], a);
        a = fmaf(wa.z, hk[2], a); a = fmaf(wa.w, hk[3], a);
        a = fmaf(wb.x, hk[4], a); a = fmaf(wb.y, hk[5], a);
        a = fmaf(wb.z, hk[6], a); a = fmaf(wb.w, hk[7], a);
        a += __shfl_xor(a, 1, 64);
        a += __shfl_xor(a, 2, 64);
        a += __shfl_xor(a, 4, 64);
        float bj = b4[j];
        if (o == 0) hB[j] = softplus(a + bj);
    }
    __syncthreads();

    // L5: 32 -> 1, +1.0 (wave 0); release-publish entry (distinct addr)
    if (tid < 64) {
        float a = (lane < 32) ? hB[lane] * W5[lane] : 0.0f;
        a += __shfl_xor(a, 1, 64);
        a += __shfl_xor(a, 2, 64);
        a += __shfl_xor(a, 4, 64);
        a += __shfl_xor(a, 8, 64);
        a += __shfl_xor(a, 16, 64);
        if (lane == 0) {
            float dgv = softplus(a + b5[0]) + 1.0f;   // >= 1.0 always
            __hip_atomic_store(&dgtab[blk], dgv, __ATOMIC_RELEASE,
                               __HIP_MEMORY_SCOPE_AGENT);
        }
    }

    // ======== Prefetch this thread's t data (independent of dg) ========
    const int row     = blk >> 2;        // 0..255
    const int quarter = blk & 3;         // 0..3
    const float* tr = t + (size_t)row * NPTS;
    float*       gr = out + (size_t)row * NPTS;
    const int base  = quarter * 4096 + tid * 16;

    const float4* p = (const float4*)(tr + base);
    float4 t0 = p[0], t1 = p[1], t2 = p[2], t3 = p[3];
    const float tfirst = tr[0];          // block-uniform

    // ======== Sync: spin on own 4 dg entries (self-signaling) ========
    const float* dp = dgtab + tid * 4;
    float4 dv;
    dv.x = spin_load(dp + 0);
    dv.y = spin_load(dp + 1);
    dv.z = spin_load(dp + 2);
    dv.w = spin_load(dp + 3);

    // ======== Phase 2: build G in LDS, then map quarter row ========
    // serial inclusive prefix of 4
    float p0 = dv.x;
    float p1 = p0 + dv.y;
    float p2 = p1 + dv.z;
    float p3 = p2 + dv.w;
    float s  = p3;

    // wave scan of per-thread totals
    float v = s;
#pragma unroll
    for (int d = 1; d < 64; d <<= 1) {
        float u = __shfl_up(v, d, 64);
        if (lane >= d) v += u;
    }
    if (lane == 63) woffs[wave] = v;
    if (tid == 0) shdg0 = dv.x;          // dg0 broadcast via LDS
    __syncthreads();
    float excl = v - s;
#pragma unroll
    for (int w = 0; w < 3; ++w)
        excl += (w < wave) ? woffs[w] : 0.0f;
    const float dg0 = shdg0;

    // write G slice: G[i] = h*(P[i] - (dg0+dg[i])/2)
    const float h = 10.0f / (float)(TS - 1);
    float* myG = &Gl[tid * GPAD];
    myG[0] = h * (excl + p0 - 0.5f * (dg0 + dv.x));
    myG[1] = h * (excl + p1 - 0.5f * (dg0 + dv.y));
    myG[2] = h * (excl + p2 - 0.5f * (dg0 + dv.z));
    myG[3] = h * (excl + p3 - 0.5f * (dg0 + dv.w));
    __syncthreads();

    // map 4096 t's (quarter row), t already in registers
    const float G0 = G_lookup(Gl, tfirst);

    float4* g4 = (float4*)(gr + base);
    float4 o;
    o.x = G_lookup(Gl, t0.x) - G0;
    o.y = G_lookup(Gl, t0.y) - G0;
    o.z = G_lookup(Gl, t0.z) - G0;
    o.w = G_lookup(Gl, t0.w) - G0;
    g4[0] = o;
    o.x = G_lookup(Gl, t1.x) - G0;
    o.y = G_lookup(Gl, t1.y) - G0;
    o.z = G_lookup(Gl, t1.z) - G0;
    o.w = G_lookup(Gl, t1.w) - G0;
    g4[1] = o;
    o.x = G_lookup(Gl, t2.x) - G0;
    o.y = G_lookup(Gl, t2.y) - G0;
    o.z = G_lookup(Gl, t2.z) - G0;
    o.w = G_lookup(Gl, t2.w) - G0;
    g4[2] = o;
    o.x = G_lookup(Gl, t3.x) - G0;
    o.y = G_lookup(Gl, t3.y) - G0;
    o.z = G_lookup(Gl, t3.z) - G0;
    o.w = G_lookup(Gl, t3.w) - G0;
    g4[3] = o;
}

extern "C" void kernel_launch(void* const* d_in, const int* in_sizes, int n_in,
                              void* d_out, int out_size, void* d_ws, size_t ws_size,
                              hipStream_t stream)
{
    const float* t  = (const float*)d_in[0];
    const float* W1 = (const float*)d_in[1];
    const float* b1 = (const float*)d_in[2];
    const float* W2 = (const float*)d_in[3];
    const float* b2 = (const float*)d_in[4];
    const float* W3 = (const float*)d_in[5];
    const float* b3 = (const float*)d_in[6];
    const float* W4 = (const float*)d_in[7];
    const float* b4 = (const float*)d_in[8];
    const float* W5 = (const float*)d_in[9];
    const float* b5 = (const float*)d_in[10];
    float* dgtab = (float*)d_ws;    // 4 KB, poisoned 0xAA -> self-signaling
    float* out   = (float*)d_out;

    fused<<<NROWS * 4, 256, 0, stream>>>(t, W1, b1, W2, b2, W3, b3, W4, b4,
                                         W5, b5, dgtab, out);
}

// Round 11
// 93.393 us; speedup vs baseline: 1.5552x; 1.2629x over previous
//
#include <hip/hip_runtime.h>
#include <math.h>

#define TS 1024               // dg/G table size == kernel-A grid
#define NPTS 16384            // N per row
#define NROWS 256             // B
#define GPAD 5                // G entry i stored at (i>>2)*5 + (i&3); gcd(5,32)=1

// softplus via hardware transcendentals (v_exp_f32 / v_log_f32)
__device__ __forceinline__ float softplus(float x) {
    float ax = fabsf(x);
    return fmaxf(x, 0.0f) + __logf(1.0f + __expf(-ax));
}

// Kernel A: dg table, ONE entry per block (R10 phase-1 structure, proven).
// 1024 blocks cover all 256 CUs (vs R8's 32-block latency chain); weights
// read per-lane from VMEM (L2-hot after first touch per XCD); layer
// reductions via shfl_xor; 5 cheap barriers. Plain store -- kernel
// boundary provides visibility (no atomics: R6/R9/R10 showed any
// in-kernel cross-XCD sync costs 35-80 us on this chip).
__global__ __launch_bounds__(256, 4) void dg_entry(
    const float* __restrict__ W1, const float* __restrict__ b1,
    const float* __restrict__ W2, const float* __restrict__ b2,
    const float* __restrict__ W3, const float* __restrict__ b3,
    const float* __restrict__ W4, const float* __restrict__ b4,
    const float* __restrict__ W5, const float* __restrict__ b5,
    float* __restrict__ dgtab)
{
    __shared__ float hA[64], hB[64];

    const int tid  = threadIdx.x;
    const int lane = tid & 63;
    const int blk  = blockIdx.x;

    const float te = 10.0f * (float)blk / (float)(TS - 1);

    // L1: 1 -> 32 (threads 0..31)
    if (tid < 32) hA[tid] = softplus(fmaf(te, W1[tid], b1[tid]));
    __syncthreads();

    // L2: 32 -> 64. j = tid>>2, k-quarter q = tid&3 (8 k's each)
    {
        const int j = tid >> 2, q = tid & 3;
        const float4* wp = (const float4*)(W2 + j * 32 + q * 8);
        float4 wa = wp[0], wb = wp[1];
        const float* hk = hA + q * 8;
        float a = 0.0f;
        a = fmaf(wa.x, hk[0], a); a = fmaf(wa.y, hk[1], a);
        a = fmaf(wa.z, hk[2], a); a = fmaf(wa.w, hk[3], a);
        a = fmaf(wb.x, hk[4], a); a = fmaf(wb.y, hk[5], a);
        a = fmaf(wb.z, hk[6], a); a = fmaf(wb.w, hk[7], a);
        a += __shfl_xor(a, 1, 64);
        a += __shfl_xor(a, 2, 64);
        float bj = b2[j];
        if (q == 0) hB[j] = softplus(a + bj);
    }
    __syncthreads();

    // L3: 64 -> 64. j = tid>>2, k-quarter q = tid&3 (16 k's each)
    {
        const int j = tid >> 2, q = tid & 3;
        const float4* wp = (const float4*)(W3 + j * 64 + q * 16);
        const float* hk = hB + q * 16;
        float a = 0.0f;
#pragma unroll
        for (int m = 0; m < 4; ++m) {
            float4 wv = wp[m];
            a = fmaf(wv.x, hk[m * 4 + 0], a);
            a = fmaf(wv.y, hk[m * 4 + 1], a);
            a = fmaf(wv.z, hk[m * 4 + 2], a);
            a = fmaf(wv.w, hk[m * 4 + 3], a);
        }
        a += __shfl_xor(a, 1, 64);
        a += __shfl_xor(a, 2, 64);
        float bj = b3[j];
        if (q == 0) hA[j] = softplus(a + bj);
    }
    __syncthreads();

    // L4: 64 -> 32. j = tid>>3, k-eighth o = tid&7 (8 k's each)
    {
        const int j = tid >> 3, o = tid & 7;
        const float4* wp = (const float4*)(W4 + j * 64 + o * 8);
        float4 wa = wp[0], wb = wp[1];
        const float* hk = hA + o * 8;
        float a = 0.0f;
        a = fmaf(wa.x, hk[0], a); a = fmaf(wa.y, hk[1], a);
        a = fmaf(wa.z, hk[2], a); a = fmaf(wa.w, hk[3], a);
        a = fmaf(wb.x, hk[4], a); a = fmaf(wb.y, hk[5], a);
        a = fmaf(wb.z, hk[6], a); a = fmaf(wb.w, hk[7], a);
        a += __shfl_xor(a, 1, 64);
        a += __shfl_xor(a, 2, 64);
        a += __shfl_xor(a, 4, 64);
        float bj = b4[j];
        if (o == 0) hB[j] = softplus(a + bj);
    }
    __syncthreads();

    // L5: 32 -> 1, +1.0 (wave 0), plain store
    if (tid < 64) {
        float a = (lane < 32) ? hB[lane] * W5[lane] : 0.0f;
        a += __shfl_xor(a, 1, 64);
        a += __shfl_xor(a, 2, 64);
        a += __shfl_xor(a, 4, 64);
        a += __shfl_xor(a, 8, 64);
        a += __shfl_xor(a, 16, 64);
        if (lane == 0)
            dgtab[blk] = softplus(a + b5[0]) + 1.0f;
    }
}

// G-table lookup from grouped-pad LDS: entry i at (i>>2)*GPAD + (i&3)
__device__ __forceinline__ float G_lookup(const float* __restrict__ Gl, float t) {
    const float scale = (float)(TS - 1) / 10.0f;
    float x = t * scale;
    x = fminf(fmaxf(x, 0.0f), (float)(TS - 1));
    int i = (int)x;
    if (i > TS - 2) i = TS - 2;
    float f = x - (float)i;
    int i1 = i + 1;
    float a = Gl[(i  >> 2) * GPAD + (i  & 3)];
    float b = Gl[(i1 >> 2) * GPAD + (i1 & 3)];
    return fmaf(b - a, f, a);
}

// Kernel B: g[b,j] = G(t[b,j]) - G(t[b,0]) -- elementwise map, no scan.
// 2048 blocks x 256 threads, 8 elems/thread (8 blocks/CU for latency
// hiding). Prelude: build 1024-entry antiderivative G in LDS (float4 dg
// load, 4-elem prefix, wave+block scan, stride-5 grouped writes =
// conflict-free), then stream: 2 float4 t loads, 8 LDS lerps, 2 float4
// stores.
__global__ __launch_bounds__(256, 8) void g_map(
    const float* __restrict__ t,
    const float* __restrict__ dgtab,
    float* __restrict__ out)
{
    __shared__ float Gl[(TS / 4) * GPAD];   // 1280 floats = 5 KB
    __shared__ float woffs[4];

    const int tid  = threadIdx.x;
    const int lane = tid & 63;
    const int wave = tid >> 6;

    // ---- prelude: thread's 4 consecutive dg entries ----
    float4 dv = ((const float4*)dgtab)[tid];
    const float dg0 = dgtab[0];   // block-uniform -> scalar load

    float p0 = dv.x;
    float p1 = p0 + dv.y;
    float p2 = p1 + dv.z;
    float p3 = p2 + dv.w;
    float s  = p3;

    float v = s;
#pragma unroll
    for (int d = 1; d < 64; d <<= 1) {
        float u = __shfl_up(v, d, 64);
        if (lane >= d) v += u;
    }
    if (lane == 63) woffs[wave] = v;
    __syncthreads();
    float excl = v - s;
#pragma unroll
    for (int w = 0; w < 3; ++w)
        excl += (w < wave) ? woffs[w] : 0.0f;

    // G[i] = h*(P[i] - (dg0+dg[i])/2)
    const float h = 10.0f / (float)(TS - 1);
    float* myG = &Gl[tid * GPAD];
    myG[0] = h * (excl + p0 - 0.5f * (dg0 + dv.x));
    myG[1] = h * (excl + p1 - 0.5f * (dg0 + dv.y));
    myG[2] = h * (excl + p2 - 0.5f * (dg0 + dv.z));
    myG[3] = h * (excl + p3 - 0.5f * (dg0 + dv.w));
    __syncthreads();

    // ---- map 2048 t's (eighth of a row) ----
    const int row   = blockIdx.x >> 3;        // 0..255
    const int chunk = blockIdx.x & 7;         // 0..7
    const float* tr = t + (size_t)row * NPTS;
    float*       gr = out + (size_t)row * NPTS;
    const int base  = chunk * 2048 + tid * 8;

    const float G0 = G_lookup(Gl, tr[0]);     // tr[0] block-uniform

    const float4* p = (const float4*)(tr + base);
    float4 t0 = p[0], t1 = p[1];

    float4* g4 = (float4*)(gr + base);
    float4 o;
    o.x = G_lookup(Gl, t0.x) - G0;
    o.y = G_lookup(Gl, t0.y) - G0;
    o.z = G_lookup(Gl, t0.z) - G0;
    o.w = G_lookup(Gl, t0.w) - G0;
    g4[0] = o;
    o.x = G_lookup(Gl, t1.x) - G0;
    o.y = G_lookup(Gl, t1.y) - G0;
    o.z = G_lookup(Gl, t1.z) - G0;
    o.w = G_lookup(Gl, t1.w) - G0;
    g4[1] = o;
}

extern "C" void kernel_launch(void* const* d_in, const int* in_sizes, int n_in,
                              void* d_out, int out_size, void* d_ws, size_t ws_size,
                              hipStream_t stream)
{
    const float* t  = (const float*)d_in[0];
    const float* W1 = (const float*)d_in[1];
    const float* b1 = (const float*)d_in[2];
    const float* W2 = (const float*)d_in[3];
    const float* b2 = (const float*)d_in[4];
    const float* W3 = (const float*)d_in[5];
    const float* b3 = (const float*)d_in[6];
    const float* W4 = (const float*)d_in[7];
    const float* b4 = (const float*)d_in[8];
    const float* W5 = (const float*)d_in[9];
    const float* b5 = (const float*)d_in[10];
    float* dgtab = (float*)d_ws;    // 4 KB
    float* out   = (float*)d_out;

    dg_entry<<<TS, 256, 0, stream>>>(W1, b1, W2, b2, W3, b3, W4, b4, W5, b5, dgtab);
    g_map<<<NROWS * 8, 256, 0, stream>>>(t, dgtab, out);
}